// Round 6
// baseline (703.196 us; speedup 1.0000x reference)
//
#include <hip/hip_runtime.h>
#include <hip/hip_bf16.h>

typedef unsigned short u16;
typedef __attribute__((ext_vector_type(4))) float f32x4;
typedef __attribute__((ext_vector_type(8))) short bf16x8;
typedef __attribute__((ext_vector_type(4))) unsigned short u16x4;

#define N 8192
#define LOG2E 1.4426950408889634f

__device__ __forceinline__ float bf2f(u16 u){
  union { float f; unsigned int i; } v; v.i = ((unsigned int)u) << 16; return v.f;
}
__device__ __forceinline__ u16 f2bf(float f){
  union { float f; unsigned int i; } v; v.f = f;
  unsigned int r = v.i + 0x7fffu + ((v.i >> 16) & 1u);
  return (u16)(r >> 16);
}
__device__ __forceinline__ f32x4 mfma16(bf16x8 a, bf16x8 b, f32x4 c){
  return __builtin_amdgcn_mfma_f32_16x16x32_bf16(a, b, c, 0, 0, 0);
}
__device__ __forceinline__ unsigned int fkey_enc(float f){
  unsigned int u = __float_as_uint(f);
  return (u & 0x80000000u) ? ~u : (u | 0x80000000u);
}
__device__ __forceinline__ float fkey_dec(unsigned int k){
  unsigned int u = (k & 0x80000000u) ? (k ^ 0x80000000u) : ~k;
  return __uint_as_float(u);
}
__device__ __forceinline__ void gload16(const void* g, void* l){
  __builtin_amdgcn_global_load_lds(
      (const __attribute__((address_space(1))) unsigned int*)(g),
      (__attribute__((address_space(3))) unsigned int*)(l), 16, 0, 0);
}

// ---------------- pack adj -> bitmask [N][1024B], bytes permuted [0,4,1,5,2,6,3,7] ----------------
// byte for (t, k2, g4) sits at t*8 + g4*2 + k2 -> attn reads one ushort per (row,t)
__global__ __launch_bounds__(256) void k_pack(const int* __restrict__ adj,
                                              unsigned long long* __restrict__ packed){
  const int wid = blockIdx.x * 4 + (threadIdx.x >> 6);
  const int lane = threadIdx.x & 63;
  const size_t base = (size_t)wid * 128;
  #pragma unroll 4
  for (int g = 0; g < 128; ++g){
    const size_t grp = base + g;
    const int v = adj[grp * 64 + lane];
    const unsigned long long m = __ballot(v != 0);
    if (lane == 0){
      const unsigned int lo = (unsigned int)m, hi = (unsigned int)(m >> 32);
      const unsigned int olo = __builtin_amdgcn_perm(hi, lo, 0x05010400u);
      const unsigned int ohi = __builtin_amdgcn_perm(hi, lo, 0x07030602u);
      packed[grp] = ((unsigned long long)ohi << 32) | olo;
    }
  }
}

// ---------------- fused prep: x->bf16(+comb), 4 transposes, wa vectors, zero-init ----------------
__global__ __launch_bounds__(256) void k_prep(
    const float* __restrict__ x, const float* __restrict__ Wh, const float* __restrict__ Wo,
    const float* __restrict__ g1, const float* __restrict__ g2,
    const float* __restrict__ ah, const float* __restrict__ ao,
    u16* __restrict__ xbf, u16* __restrict__ comb,
    u16* __restrict__ wth, u16* __restrict__ wot,
    u16* __restrict__ g1t, u16* __restrict__ g2t,
    float* __restrict__ wa, unsigned int* __restrict__ fkey, float* __restrict__ csum)
{
  const int b = blockIdx.x, t = threadIdx.x;
  if (b < 1024){
    const int idx = b * 256 + t;
    f32x4 v = ((const f32x4*)x)[idx];
    u16x4 h;
    #pragma unroll
    for (int e = 0; e < 4; ++e) h[e] = f2bf(v[e]);
    ((u16x4*)xbf)[idx] = h;
    const int i = idx >> 5, c4 = (idx & 31) * 4;
    *(u16x4*)(comb + (size_t)i * 256 + c4) = h;
  } else if (b < 1152){
    const int rel = (b - 1024) * 256 + t;
    const int head = rel >> 14, win = rel & 16383;
    const int n = win >> 7, k = win & 127;
    wth[rel] = f2bf(Wh[(head << 14) + k * 128 + n]);
  } else if (b < 1280){
    const int rel = (b - 1152) * 256 + t;
    const int n = rel >> 8, k = rel & 255;
    wot[rel] = f2bf(Wo[k * 128 + n]);
  } else if (b < 1536){
    const int rel = (b - 1280) * 256 + t;
    const int n = rel >> 8, k = rel & 255;
    g1t[rel] = f2bf(g1[k * 256 + n]);
  } else if (b < 1664){
    const int rel = (b - 1536) * 256 + t;
    const int n = rel >> 8, k = rel & 255;
    g2t[rel] = f2bf(g2[k * 128 + n]);
  } else if (b < 1667){
    const int z = b - 1664;
    if (z < 2){
      if (t < 128){
        float a1 = 0.f, a2 = 0.f;
        for (int c = 0; c < 128; ++c){
          const float w = Wh[(size_t)z * 16384 + t * 128 + c];
          a1 += w * ah[z * 256 + c];
          a2 += w * ah[z * 256 + 128 + c];
        }
        wa[z * 128 + t] = a1; wa[256 + z * 128 + t] = a2;
      }
    } else {
      if (t < 256){
        float a1 = 0.f, a2 = 0.f;
        for (int c = 0; c < 128; ++c){
          const float w = Wo[(size_t)t * 128 + c];
          a1 += w * ao[c];
          a2 += w * ao[128 + c];
        }
        wa[512 + t] = a1; wa[768 + t] = a2;
      }
    }
  } else {
    if (t < 128) csum[t] = 0.f;
    if (t < 4) fkey[t] = 0u;
  }
}

// ---------------- gemv layer1 + keyed atomic max ----------------
__global__ __launch_bounds__(256) void k_gemv1(const float* __restrict__ x, const float* __restrict__ wa,
                                               float* __restrict__ f1s, float* __restrict__ f2s,
                                               unsigned int* __restrict__ fkey){
  const int h = blockIdx.y;
  const float* wa1 = wa + h * 128;
  const float* wa2 = wa + 256 + h * 128;
  const int lane = threadIdx.x & 63, w = threadIdx.x >> 6;
  const int r16 = lane & 15, g4 = lane >> 4;
  const int row = blockIdx.x * 16 + w * 4 + g4;
  const float* xr = x + (size_t)row * 128 + r16 * 8;
  f32x4 x0 = *(const f32x4*)(xr);
  f32x4 x1 = *(const f32x4*)(xr + 4);
  f32x4 wA0 = *(const f32x4*)(wa1 + r16 * 8);
  f32x4 wA1 = *(const f32x4*)(wa1 + r16 * 8 + 4);
  f32x4 wB0 = *(const f32x4*)(wa2 + r16 * 8);
  f32x4 wB1 = *(const f32x4*)(wa2 + r16 * 8 + 4);
  float d1 = 0.f, d2 = 0.f;
  #pragma unroll
  for (int e = 0; e < 4; ++e){
    d1 += x0[e] * wA0[e] + x1[e] * wA1[e];
    d2 += x0[e] * wB0[e] + x1[e] * wB1[e];
  }
  d1 += __shfl_xor(d1, 1); d1 += __shfl_xor(d1, 2); d1 += __shfl_xor(d1, 4); d1 += __shfl_xor(d1, 8);
  d2 += __shfl_xor(d2, 1); d2 += __shfl_xor(d2, 2); d2 += __shfl_xor(d2, 4); d2 += __shfl_xor(d2, 8);
  const float d1s = d1 * LOG2E, d2s = d2 * LOG2E;
  if (r16 == 0){
    f1s[(size_t)h * N + row] = d1s;
    f2s[(size_t)h * N + row] = d2s;
  }
  float m = d2s;
  m = fmaxf(m, __shfl_xor(m, 16)); m = fmaxf(m, __shfl_xor(m, 32));
  if (lane == 0) atomicMax(fkey + h, fkey_enc(m));
}

// ---------------- gemv layer2 + keyed atomic max ----------------
__global__ __launch_bounds__(256) void k_gemv2(const u16* __restrict__ hbf,
                                               const float* __restrict__ wao1, const float* __restrict__ wao2,
                                               float* __restrict__ f1s, float* __restrict__ f2s,
                                               unsigned int* __restrict__ fkey){
  const int lane = threadIdx.x & 63, w = threadIdx.x >> 6;
  const int r16 = lane & 15, g4 = lane >> 4;
  const int row = blockIdx.x * 16 + w * 4 + g4;
  bf16x8 h0 = *(const bf16x8*)(hbf + (size_t)row * 256 + r16 * 16);
  bf16x8 h1 = *(const bf16x8*)(hbf + (size_t)row * 256 + r16 * 16 + 8);
  float d1 = 0.f, d2 = 0.f;
  #pragma unroll
  for (int e = 0; e < 8; ++e){
    const float v0 = bf2f((u16)h0[e]), v1 = bf2f((u16)h1[e]);
    d1 += v0 * wao1[r16 * 16 + e] + v1 * wao1[r16 * 16 + 8 + e];
    d2 += v0 * wao2[r16 * 16 + e] + v1 * wao2[r16 * 16 + 8 + e];
  }
  d1 += __shfl_xor(d1, 1); d1 += __shfl_xor(d1, 2); d1 += __shfl_xor(d1, 4); d1 += __shfl_xor(d1, 8);
  d2 += __shfl_xor(d2, 1); d2 += __shfl_xor(d2, 2); d2 += __shfl_xor(d2, 4); d2 += __shfl_xor(d2, 8);
  const float d1s = d1 * LOG2E, d2s = d2 * LOG2E;
  if (r16 == 0){
    f1s[row] = d1s;
    f2s[row] = d2s;
  }
  float m = d2s;
  m = fmaxf(m, __shfl_xor(m, 16)); m = fmaxf(m, __shfl_xor(m, 32));
  if (lane == 0) atomicMax(fkey, fkey_enc(m));
}

// ---------------- GEMM -> tiled-swizzled whT: per head, 128 tiles of 16KB ----------------
// tile t holds channels c=0..127 x j'=0..63 (j=t*64+j'), u16 index: c*64 + (j' ^ ((c&7)<<3))
__global__ __launch_bounds__(256) void k_gemm_at(const u16* __restrict__ A_all, const u16* __restrict__ B,
                                                 u16* __restrict__ outT_all, int K){
  const int head = blockIdx.y;
  const u16* A = A_all + (size_t)head * 128 * K;
  u16* outT = outT_all + (size_t)head * 1048576;
  const int lane = threadIdx.x & 63, w = threadIdx.x >> 6;
  const int r16 = lane & 15, g4 = lane >> 4;
  const size_t ib = (size_t)blockIdx.x * 64 + w * 16;
  f32x4 acc[8];
  #pragma unroll
  for (int cg = 0; cg < 8; ++cg) acc[cg] = (f32x4){0,0,0,0};
  for (int kk = 0; kk < K; kk += 32){
    bf16x8 b = *(const bf16x8*)(B + (ib + r16) * (size_t)K + kk + g4 * 8);
    #pragma unroll
    for (int cg = 0; cg < 8; ++cg){
      bf16x8 a = *(const bf16x8*)(A + (size_t)(cg * 16 + r16) * K + kk + g4 * 8);
      acc[cg] = mfma16(a, b, acc[cg]);
    }
  }
  const int jp = w * 16 + r16;
  u16* tb = outT + (size_t)blockIdx.x * 8192;
  #pragma unroll
  for (int cg = 0; cg < 8; ++cg)
    #pragma unroll
    for (int q = 0; q < 4; ++q){
      const int c = cg * 16 + g4 * 4 + q;
      tb[c * 64 + (jp ^ ((c & 7) << 3))] = f2bf(acc[cg][q]);
    }
}

// ---------------- attention: LDS dbuf staging, 4 waves x 32 rows, low reg pressure ----------------
// PART tile layout (16-row tile, 2048 u16): elem(r,c) at ((c>>4)*4 + (r&3))*64 + (r>>2)*16 + (c&15)
template<int S>
__global__ __launch_bounds__(256, 2) void k_attn(
    const unsigned char* __restrict__ pk,
    const u16* __restrict__ whT_all,       // tiled-swizzled [H][128 tiles][8192] u16
    const float* __restrict__ f1_all, const float* __restrict__ f2_all,
    const unsigned int* __restrict__ fkey,
    u16* __restrict__ part, float* __restrict__ pl)
{
  __shared__ __align__(16) u16 tile[2][8192];   // 2 x 16 KB
  const int h = blockIdx.z;
  const int s = blockIdx.y;
  const float* f2 = f2_all + (size_t)h * N;
  const float fmax = fkey_dec(fkey[h]);
  const int w = threadIdx.x >> 6;
  const int lane = threadIdx.x & 63;
  const int r16 = lane & 15, g4 = lane >> 4;
  const size_t ibase = (size_t)blockIdx.x * 128 + w * 32;
  constexpr int TPS = 128 / S;
  const int t0 = s * TPS, t1 = t0 + TPS;
  const char* gt = (const char*)whT_all + (size_t)h * 2097152;

  float c1[2], c2[2], lsum[2];
  f32x4 acc[2][8];
  #pragma unroll
  for (int rg = 0; rg < 2; ++rg){
    const float f1v = f1_all[(size_t)h * N + ibase + rg * 16 + r16];
    const float y = f1v + fmax;
    const float mrow = fmaxf(y, 0.2f * y);
    c1[rg] = f1v - mrow;
    c2[rg] = fmaf(0.2f, f1v, -mrow);
    lsum[rg] = 0.f;
    #pragma unroll
    for (int ct = 0; ct < 8; ++ct) acc[rg][ct] = (f32x4){0,0,0,0};
  }

  const int swz = (r16 & 7) << 3;
  const int off0 = r16 * 64 + ((g4 * 8) ^ swz);
  const unsigned char* pkr0 = pk + (ibase + r16) * 1024 + g4 * 2;
  const unsigned char* pkr1 = pkr0 + 16 * 1024;

  auto stage = [&](int buf, int tt){
    const char* src = gt + (size_t)tt * 16384 + w * 4096 + lane * 16;
    char* dst = ((char*)&tile[0][0]) + buf * 16384 + w * 4096;
    #pragma unroll
    for (int k = 0; k < 4; ++k)
      gload16(src + k * 1024, dst + k * 1024);
  };

  stage(0, t0);
  for (int t = t0; t < t1; ++t){
    const int cur = (t - t0) & 1;
    __syncthreads();                        // tile[cur] ready, tile[cur^1] free
    if (t + 1 < t1) stage(cur ^ 1, t + 1);  // DMA next tile under compute
    const unsigned int bits0 = *(const unsigned short*)(pkr0 + t * 8);
    const unsigned int bits1 = *(const unsigned short*)(pkr1 + t * 8);
    const u16* lp = &tile[cur][0];
    #pragma unroll
    for (int k2 = 0; k2 < 2; ++k2){
      const float* fjp = f2 + t * 64 + k2 * 32 + g4 * 8;
      f32x4 fa = *(const f32x4*)(fjp);
      f32x4 fb = *(const f32x4*)(fjp + 4);
      bf16x8 pa0, pa1;
      {
        const unsigned int bb = (bits0 >> (k2 * 8)) & 0xFFu;
        union { __hip_bfloat162 h2[4]; bf16x8 v8; } u;
        #pragma unroll
        for (int xp = 0; xp < 4; ++xp){
          const float s0 = (xp < 2) ? fa[2 * xp] : fb[2 * xp - 4];
          const float s1 = (xp < 2) ? fa[2 * xp + 1] : fb[2 * xp - 3];
          float p0 = __builtin_amdgcn_exp2f(fmaxf(s0 + c1[0], fmaf(s0, 0.2f, c2[0])));
          float p1 = __builtin_amdgcn_exp2f(fmaxf(s1 + c1[0], fmaf(s1, 0.2f, c2[0])));
          p0 = ((bb >> (2 * xp)) & 1u) ? p0 : 0.f;
          p1 = ((bb >> (2 * xp + 1)) & 1u) ? p1 : 0.f;
          lsum[0] += p0 + p1;
          u.h2[xp] = __float22bfloat162_rn(make_float2(p0, p1));
        }
        pa0 = u.v8;
      }
      {
        const unsigned int bb = (bits1 >> (k2 * 8)) & 0xFFu;
        union { __hip_bfloat162 h2[4]; bf16x8 v8; } u;
        #pragma unroll
        for (int xp = 0; xp < 4; ++xp){
          const float s0 = (xp < 2) ? fa[2 * xp] : fb[2 * xp - 4];
          const float s1 = (xp < 2) ? fa[2 * xp + 1] : fb[2 * xp - 3];
          float p0 = __builtin_amdgcn_exp2f(fmaxf(s0 + c1[1], fmaf(s0, 0.2f, c2[1])));
          float p1 = __builtin_amdgcn_exp2f(fmaxf(s1 + c1[1], fmaf(s1, 0.2f, c2[1])));
          p0 = ((bb >> (2 * xp)) & 1u) ? p0 : 0.f;
          p1 = ((bb >> (2 * xp + 1)) & 1u) ? p1 : 0.f;
          lsum[1] += p0 + p1;
          u.h2[xp] = __float22bfloat162_rn(make_float2(p0, p1));
        }
        pa1 = u.v8;
      }
      const int offk = off0 ^ (k2 << 5);
      #pragma unroll
      for (int ct = 0; ct < 8; ++ct){
        bf16x8 b = *(const bf16x8*)(lp + offk + ct * 1024);
        acc[0][ct] = mfma16(pa0, b, acc[0][ct]);
        acc[1][ct] = mfma16(pa1, b, acc[1][ct]);
      }
    }
  }

  const int plane = h * S + s;
  #pragma unroll
  for (int rg = 0; rg < 2; ++rg){
    const int tile_row = (int)(ibase >> 4) + rg;
    u16* pp = part + ((size_t)plane * 512 + tile_row) * 2048;
    #pragma unroll
    for (int ct = 0; ct < 8; ++ct)
      #pragma unroll
      for (int q = 0; q < 4; ++q)
        pp[(ct * 4 + q) * 64 + lane] = f2bf(acc[rg][ct][q]);
    float lv = lsum[rg];
    lv += __shfl_xor(lv, 16); lv += __shfl_xor(lv, 32);
    if (lane < 16) pl[(size_t)plane * N + ibase + rg * 16 + lane] = lv;
  }
}

// ---------------- merge partials: sum, normalize, elu, write ----------------
template<int S, bool L2>
__global__ __launch_bounds__(256) void k_attn_merge(
    const u16* __restrict__ part, const float* __restrict__ pl,
    u16* __restrict__ hbf, float* __restrict__ nodeout, u16* __restrict__ comb)
{
  const int h = blockIdx.y;
  const int idx = blockIdx.x * 256 + threadIdx.x;
  const int i = idx >> 5, c4 = (idx & 31) * 4;
  const int tl = i >> 4, r = i & 15;
  const size_t off = (size_t)tl * 2048 + (size_t)(((c4 >> 4) * 4 + (r & 3)) * 64 + ((r >> 2) & 3) * 16 + (c4 & 15));
  f32x4 a = (f32x4){0,0,0,0};
  float L = 0.f;
  #pragma unroll
  for (int s = 0; s < S; ++s){
    const size_t plane = h * S + s;
    u16x4 v = *(const u16x4*)(part + plane * (size_t)(N * 128) + off);
    a[0] += bf2f(v[0]); a[1] += bf2f(v[1]); a[2] += bf2f(v[2]); a[3] += bf2f(v[3]);
    L += pl[plane * (size_t)N + i];
  }
  const float linv = 1.f / L;
  u16x4 hv;
  #pragma unroll
  for (int e = 0; e < 4; ++e){
    float o = a[e] * linv;
    o = (o > 0.f) ? o : (__expf(o) - 1.f);
    a[e] = o;
    hv[e] = f2bf(o);
  }
  if constexpr (!L2){
    *(u16x4*)(hbf + (size_t)i * 256 + h * 128 + c4) = hv;
  } else {
    *(f32x4*)(nodeout + (size_t)i * 128 + c4) = a;
    *(u16x4*)(comb + (size_t)i * 256 + 128 + c4) = hv;
  }
}

// ---------------- row-major GEMM + bias + relu (+optional column-sum) ----------------
template<bool STORE, bool COLSUM>
__global__ __launch_bounds__(256) void k_gemm_row(
    const u16* __restrict__ A, const u16* __restrict__ BT,
    const float* __restrict__ bias,
    u16* __restrict__ out, float* __restrict__ csum,
    int K, int Ntot)
{
  const int lane = threadIdx.x & 63, w = threadIdx.x >> 6;
  const int r16 = lane & 15, g4 = lane >> 4;
  const size_t rbase = (size_t)blockIdx.x * 64 + w * 16;
  const int cbase = blockIdx.y * 128;
  f32x4 acc[8];
  #pragma unroll
  for (int ct = 0; ct < 8; ++ct) acc[ct] = (f32x4){0,0,0,0};
  for (int kk = 0; kk < K; kk += 32){
    bf16x8 af = *(const bf16x8*)(A + (rbase + r16) * (size_t)K + kk + g4 * 8);
    #pragma unroll
    for (int ct = 0; ct < 8; ++ct){
      bf16x8 bfr = *(const bf16x8*)(BT + (size_t)(cbase + ct * 16 + r16) * K + kk + g4 * 8);
      acc[ct] = mfma16(af, bfr, acc[ct]);
    }
  }
  #pragma unroll
  for (int ct = 0; ct < 8; ++ct){
    const float bv = bias[cbase + ct * 16 + r16];
    float sacc = 0.f;
    #pragma unroll
    for (int q = 0; q < 4; ++q){
      float v = acc[ct][q] + bv;
      v = fmaxf(v, 0.f);
      if constexpr (STORE)
        out[(rbase + g4 * 4 + q) * (size_t)Ntot + cbase + ct * 16 + r16] = f2bf(v);
      sacc += v;
    }
    if constexpr (COLSUM){
      sacc += __shfl_xor(sacc, 16); sacc += __shfl_xor(sacc, 32);
      if (lane < 16) atomicAdd(&csum[cbase + ct * 16 + lane], sacc);
    }
  }
}

__global__ void k_final(const float* __restrict__ csum, float* __restrict__ out){
  out[threadIdx.x] = csum[threadIdx.x] * (1.f / 8192.f);
}

// ---------------- host launch ----------------
extern "C" void kernel_launch(void* const* d_in, const int* in_sizes, int n_in,
                              void* d_out, int out_size, void* d_ws, size_t ws_size,
                              hipStream_t stream) {
  const int*   adj = (const int*)d_in[0];
  const float* x   = (const float*)d_in[1];
  const float* Wh  = (const float*)d_in[2];
  const float* ah  = (const float*)d_in[3];
  const float* Wo  = (const float*)d_in[4];
  const float* ao  = (const float*)d_in[5];
  const float* g1  = (const float*)d_in[6];
  const float* b1  = (const float*)d_in[7];
  const float* g2  = (const float*)d_in[8];
  const float* b2  = (const float*)d_in[9];
  float* outp = (float*)d_out;
  char* ws = (char*)d_ws;

  constexpr size_t PK   = 0;          //  8,388,608  packed adj bits (permuted)
  constexpr size_t PART = 8388608;    // 16,777,216  bf16 partials [8 planes][512 tiles][2048]
  constexpr size_t PL   = 25165824;   //    262,144  l partials [8][8192] f32
  constexpr size_t XBF  = 25427968;   //  2,097,152  x bf16
  constexpr size_t WHT1 = 27525120;   //  4,194,304  Wh^T L1 tiled-swz [2][128][8192]u16
  constexpr size_t WHT2 = 31719424;   //  2,097,152  Wh^T L2 tiled-swz
  constexpr size_t HBF  = 33816576;   //  4,194,304  h bf16 [8192][256]
  constexpr size_t COMB = 38010880;   //  4,194,304  combined [8192][256]
  constexpr size_t H1RO = WHT1;       //  alias: WhT1 dead after attn1
  constexpr size_t F1S  = 42205184;   //     65,536
  constexpr size_t F2S  = 42270720;   //     65,536
  constexpr size_t CSUM = 42336256;   //        512
  constexpr size_t WTH  = 42336768;   //     65,536
  constexpr size_t WOT  = 42402304;   //     65,536
  constexpr size_t G1T  = 42467840;   //    131,072
  constexpr size_t G2T  = 42598912;   //     65,536
  constexpr size_t WA   = 42664448;   //      4,096
  constexpr size_t FKEY = 42668544;   //         16

  k_pack<<<2048, 256, 0, stream>>>(adj, (unsigned long long*)(ws + PK));
  k_prep<<<1668, 256, 0, stream>>>(x, Wh, Wo, g1, g2, ah, ao,
      (u16*)(ws + XBF), (u16*)(ws + COMB), (u16*)(ws + WTH), (u16*)(ws + WOT),
      (u16*)(ws + G1T), (u16*)(ws + G2T),
      (float*)(ws + WA), (unsigned int*)(ws + FKEY), (float*)(ws + CSUM));

  // layer 1
  k_gemv1<<<dim3(512, 2), 256, 0, stream>>>(x, (const float*)(ws + WA),
      (float*)(ws + F1S), (float*)(ws + F2S), (unsigned int*)(ws + FKEY));
  k_gemm_at<<<dim3(128, 2), 256, 0, stream>>>((const u16*)(ws + WTH), (const u16*)(ws + XBF),
                                              (u16*)(ws + WHT1), 128);
  k_attn<4><<<dim3(64, 4, 2), 256, 0, stream>>>(
      (const unsigned char*)(ws + PK), (const u16*)(ws + WHT1),
      (const float*)(ws + F1S), (const float*)(ws + F2S), (const unsigned int*)(ws + FKEY),
      (u16*)(ws + PART), (float*)(ws + PL));
  k_attn_merge<4, false><<<dim3(1024, 2), 256, 0, stream>>>(
      (const u16*)(ws + PART), (const float*)(ws + PL),
      (u16*)(ws + HBF), nullptr, nullptr);

  // layer 2
  k_gemv2<<<dim3(512, 1), 256, 0, stream>>>((const u16*)(ws + HBF),
      (const float*)(ws + WA) + 512, (const float*)(ws + WA) + 768,
      (float*)(ws + F1S), (float*)(ws + F2S), (unsigned int*)(ws + FKEY) + 2);
  k_gemm_at<<<dim3(128, 1), 256, 0, stream>>>((const u16*)(ws + WOT), (const u16*)(ws + HBF),
                                              (u16*)(ws + WHT2), 256);
  k_attn<8><<<dim3(64, 8, 1), 256, 0, stream>>>(
      (const unsigned char*)(ws + PK), (const u16*)(ws + WHT2),
      (const float*)(ws + F1S), (const float*)(ws + F2S), (const unsigned int*)(ws + FKEY) + 2,
      (u16*)(ws + PART), (float*)(ws + PL));
  k_attn_merge<8, true><<<dim3(1024, 1), 256, 0, stream>>>(
      (const u16*)(ws + PART), (const float*)(ws + PL),
      nullptr, outp, (u16*)(ws + COMB));

  // readout MLP
  k_gemm_row<true, false><<<dim3(128, 2), 256, 0, stream>>>(
      (const u16*)(ws + COMB), (const u16*)(ws + G1T), b1,
      (u16*)(ws + H1RO), nullptr, 256, 256);
  k_gemm_row<false, true><<<dim3(128, 1), 256, 0, stream>>>(
      (const u16*)(ws + H1RO), (const u16*)(ws + G2T), b2,
      nullptr, (float*)(ws + CSUM), 256, 128);
  k_final<<<1, 128, 0, stream>>>((const float*)(ws + CSUM), outp + (size_t)N * 128);
}

// Round 7
// 668.104 us; speedup vs baseline: 1.0525x; 1.0525x over previous
//
#include <hip/hip_runtime.h>
#include <hip/hip_bf16.h>

typedef unsigned short u16;
typedef __attribute__((ext_vector_type(4))) float f32x4;
typedef __attribute__((ext_vector_type(8))) short bf16x8;
typedef __attribute__((ext_vector_type(4))) unsigned short u16x4;
typedef __attribute__((ext_vector_type(4))) int i32x4;

#define N 8192
#define LOG2E 1.4426950408889634f

__device__ __forceinline__ float bf2f(u16 u){
  union { float f; unsigned int i; } v; v.i = ((unsigned int)u) << 16; return v.f;
}
__device__ __forceinline__ u16 f2bf(float f){
  union { float f; unsigned int i; } v; v.f = f;
  unsigned int r = v.i + 0x7fffu + ((v.i >> 16) & 1u);
  return (u16)(r >> 16);
}
__device__ __forceinline__ f32x4 mfma16(bf16x8 a, bf16x8 b, f32x4 c){
  return __builtin_amdgcn_mfma_f32_16x16x32_bf16(a, b, c, 0, 0, 0);
}
__device__ __forceinline__ unsigned int fkey_enc(float f){
  unsigned int u = __float_as_uint(f);
  return (u & 0x80000000u) ? ~u : (u | 0x80000000u);
}
__device__ __forceinline__ float fkey_dec(unsigned int k){
  unsigned int u = (k & 0x80000000u) ? (k ^ 0x80000000u) : ~k;
  return __uint_as_float(u);
}
__device__ __forceinline__ void gload16(const void* g, void* l){
  __builtin_amdgcn_global_load_lds(
      (const __attribute__((address_space(1))) unsigned int*)(g),
      (__attribute__((address_space(3))) unsigned int*)(l), 16, 0, 0);
}

// ---------------- pack adj -> bitmask [N][1024B], permuted-byte layout ----------------
// byte at row*1024 + t*8 + g4*2 + k2 covers cols t*64 + k2*32 + g4*8 + {0..7}.
// Coalesced: each lane loads int4 (16B); ballots deinterleaved in VALU; 64B/row-chunk stores.
__global__ __launch_bounds__(256) void k_pack(const int* __restrict__ adj,
                                              unsigned char* __restrict__ pk){
  const int wid = blockIdx.x * 4 + (threadIdx.x >> 6);
  const int lane = threadIdx.x & 63;
  const int half = lane >> 5, b = lane & 31;
  const int sh0 = (b >> 3) * 16 + (b & 7) * 2;   // base bit within ballot
  const int outoff = half * 32 + ((b >> 3) << 3) + (((b & 3) << 1) | ((b >> 2) & 1));
  for (int r = 0; r < 4; ++r){
    const size_t row = (size_t)wid * 4 + r;
    const int* ar = adj + row * 8192;
    unsigned char* pr = pk + row * 1024;
    for (int it = 0; it < 16; ++it){
      i32x4 v0 = *(const i32x4*)(ar + it * 512 + lane * 4);
      i32x4 v1 = *(const i32x4*)(ar + it * 512 + 256 + lane * 4);
      unsigned long long A0 = __ballot(v0[0] != 0);
      unsigned long long A1 = __ballot(v0[1] != 0);
      unsigned long long A2 = __ballot(v0[2] != 0);
      unsigned long long A3 = __ballot(v0[3] != 0);
      unsigned long long C0 = __ballot(v1[0] != 0);
      unsigned long long C1 = __ballot(v1[1] != 0);
      unsigned long long C2 = __ballot(v1[2] != 0);
      unsigned long long C3 = __ballot(v1[3] != 0);
      const unsigned long long B0 = half ? C0 : A0;
      const unsigned long long B1 = half ? C1 : A1;
      const unsigned long long B2 = half ? C2 : A2;
      const unsigned long long B3 = half ? C3 : A3;
      unsigned int byte =
          (unsigned int)((B0 >> sh0) & 1ull)
        | ((unsigned int)((B1 >> sh0) & 1ull) << 1)
        | ((unsigned int)((B2 >> sh0) & 1ull) << 2)
        | ((unsigned int)((B3 >> sh0) & 1ull) << 3)
        | ((unsigned int)((B0 >> (sh0 + 1)) & 1ull) << 4)
        | ((unsigned int)((B1 >> (sh0 + 1)) & 1ull) << 5)
        | ((unsigned int)((B2 >> (sh0 + 1)) & 1ull) << 6)
        | ((unsigned int)((B3 >> (sh0 + 1)) & 1ull) << 7);
      pr[it * 64 + outoff] = (unsigned char)byte;
    }
  }
}

// ---------------- fused prep: x->bf16(+comb), 4 transposes, wa vectors, zero-init ----------------
__global__ __launch_bounds__(256) void k_prep(
    const float* __restrict__ x, const float* __restrict__ Wh, const float* __restrict__ Wo,
    const float* __restrict__ g1, const float* __restrict__ g2,
    const float* __restrict__ ah, const float* __restrict__ ao,
    u16* __restrict__ xbf, u16* __restrict__ comb,
    u16* __restrict__ wth, u16* __restrict__ wot,
    u16* __restrict__ g1t, u16* __restrict__ g2t,
    float* __restrict__ wa, unsigned int* __restrict__ fkey, float* __restrict__ csum)
{
  const int b = blockIdx.x, t = threadIdx.x;
  if (b < 1024){
    const int idx = b * 256 + t;
    f32x4 v = ((const f32x4*)x)[idx];
    u16x4 h;
    #pragma unroll
    for (int e = 0; e < 4; ++e) h[e] = f2bf(v[e]);
    ((u16x4*)xbf)[idx] = h;
    const int i = idx >> 5, c4 = (idx & 31) * 4;
    *(u16x4*)(comb + (size_t)i * 256 + c4) = h;
  } else if (b < 1152){
    const int rel = (b - 1024) * 256 + t;
    const int head = rel >> 14, win = rel & 16383;
    const int n = win >> 7, k = win & 127;
    wth[rel] = f2bf(Wh[(head << 14) + k * 128 + n]);
  } else if (b < 1280){
    const int rel = (b - 1152) * 256 + t;
    const int n = rel >> 8, k = rel & 255;
    wot[rel] = f2bf(Wo[k * 128 + n]);
  } else if (b < 1536){
    const int rel = (b - 1280) * 256 + t;
    const int n = rel >> 8, k = rel & 255;
    g1t[rel] = f2bf(g1[k * 256 + n]);
  } else if (b < 1664){
    const int rel = (b - 1536) * 256 + t;
    const int n = rel >> 8, k = rel & 255;
    g2t[rel] = f2bf(g2[k * 128 + n]);
  } else if (b < 1667){
    const int z = b - 1664;
    if (z < 2){
      if (t < 128){
        float a1 = 0.f, a2 = 0.f;
        for (int c = 0; c < 128; ++c){
          const float w = Wh[(size_t)z * 16384 + t * 128 + c];
          a1 += w * ah[z * 256 + c];
          a2 += w * ah[z * 256 + 128 + c];
        }
        wa[z * 128 + t] = a1; wa[256 + z * 128 + t] = a2;
      }
    } else {
      if (t < 256){
        float a1 = 0.f, a2 = 0.f;
        for (int c = 0; c < 128; ++c){
          const float w = Wo[(size_t)t * 128 + c];
          a1 += w * ao[c];
          a2 += w * ao[128 + c];
        }
        wa[512 + t] = a1; wa[768 + t] = a2;
      }
    }
  } else {
    if (t < 128) csum[t] = 0.f;
    if (t < 4) fkey[t] = 0u;
  }
}

// ---------------- gemv layer1 + keyed atomic max ----------------
__global__ __launch_bounds__(256) void k_gemv1(const float* __restrict__ x, const float* __restrict__ wa,
                                               float* __restrict__ f1s, float* __restrict__ f2s,
                                               unsigned int* __restrict__ fkey){
  const int h = blockIdx.y;
  const float* wa1 = wa + h * 128;
  const float* wa2 = wa + 256 + h * 128;
  const int lane = threadIdx.x & 63, w = threadIdx.x >> 6;
  const int r16 = lane & 15, g4 = lane >> 4;
  const int row = blockIdx.x * 16 + w * 4 + g4;
  const float* xr = x + (size_t)row * 128 + r16 * 8;
  f32x4 x0 = *(const f32x4*)(xr);
  f32x4 x1 = *(const f32x4*)(xr + 4);
  f32x4 wA0 = *(const f32x4*)(wa1 + r16 * 8);
  f32x4 wA1 = *(const f32x4*)(wa1 + r16 * 8 + 4);
  f32x4 wB0 = *(const f32x4*)(wa2 + r16 * 8);
  f32x4 wB1 = *(const f32x4*)(wa2 + r16 * 8 + 4);
  float d1 = 0.f, d2 = 0.f;
  #pragma unroll
  for (int e = 0; e < 4; ++e){
    d1 += x0[e] * wA0[e] + x1[e] * wA1[e];
    d2 += x0[e] * wB0[e] + x1[e] * wB1[e];
  }
  d1 += __shfl_xor(d1, 1); d1 += __shfl_xor(d1, 2); d1 += __shfl_xor(d1, 4); d1 += __shfl_xor(d1, 8);
  d2 += __shfl_xor(d2, 1); d2 += __shfl_xor(d2, 2); d2 += __shfl_xor(d2, 4); d2 += __shfl_xor(d2, 8);
  const float d1s = d1 * LOG2E, d2s = d2 * LOG2E;
  if (r16 == 0){
    f1s[(size_t)h * N + row] = d1s;
    f2s[(size_t)h * N + row] = d2s;
  }
  float m = d2s;
  m = fmaxf(m, __shfl_xor(m, 16)); m = fmaxf(m, __shfl_xor(m, 32));
  if (lane == 0) atomicMax(fkey + h, fkey_enc(m));
}

// ---------------- gemv layer2 + keyed atomic max ----------------
__global__ __launch_bounds__(256) void k_gemv2(const u16* __restrict__ hbf,
                                               const float* __restrict__ wao1, const float* __restrict__ wao2,
                                               float* __restrict__ f1s, float* __restrict__ f2s,
                                               unsigned int* __restrict__ fkey){
  const int lane = threadIdx.x & 63, w = threadIdx.x >> 6;
  const int r16 = lane & 15, g4 = lane >> 4;
  const int row = blockIdx.x * 16 + w * 4 + g4;
  bf16x8 h0 = *(const bf16x8*)(hbf + (size_t)row * 256 + r16 * 16);
  bf16x8 h1 = *(const bf16x8*)(hbf + (size_t)row * 256 + r16 * 16 + 8);
  float d1 = 0.f, d2 = 0.f;
  #pragma unroll
  for (int e = 0; e < 8; ++e){
    const float v0 = bf2f((u16)h0[e]), v1 = bf2f((u16)h1[e]);
    d1 += v0 * wao1[r16 * 16 + e] + v1 * wao1[r16 * 16 + 8 + e];
    d2 += v0 * wao2[r16 * 16 + e] + v1 * wao2[r16 * 16 + 8 + e];
  }
  d1 += __shfl_xor(d1, 1); d1 += __shfl_xor(d1, 2); d1 += __shfl_xor(d1, 4); d1 += __shfl_xor(d1, 8);
  d2 += __shfl_xor(d2, 1); d2 += __shfl_xor(d2, 2); d2 += __shfl_xor(d2, 4); d2 += __shfl_xor(d2, 8);
  const float d1s = d1 * LOG2E, d2s = d2 * LOG2E;
  if (r16 == 0){
    f1s[row] = d1s;
    f2s[row] = d2s;
  }
  float m = d2s;
  m = fmaxf(m, __shfl_xor(m, 16)); m = fmaxf(m, __shfl_xor(m, 32));
  if (lane == 0) atomicMax(fkey, fkey_enc(m));
}

// ---------------- GEMM -> tiled-swizzled whT: per head, 128 tiles of 16KB ----------------
// tile t: channels c x j'=0..63 (j=t*64+j'), u16 index: c*64 + (j' ^ ((c&7)<<3))
__global__ __launch_bounds__(256) void k_gemm_at(const u16* __restrict__ A_all, const u16* __restrict__ B,
                                                 u16* __restrict__ outT_all, int K){
  const int head = blockIdx.y;
  const u16* A = A_all + (size_t)head * 128 * K;
  u16* outT = outT_all + (size_t)head * 1048576;
  const int lane = threadIdx.x & 63, w = threadIdx.x >> 6;
  const int r16 = lane & 15, g4 = lane >> 4;
  const size_t ib = (size_t)blockIdx.x * 64 + w * 16;
  f32x4 acc[8];
  #pragma unroll
  for (int cg = 0; cg < 8; ++cg) acc[cg] = (f32x4){0,0,0,0};
  for (int kk = 0; kk < K; kk += 32){
    bf16x8 b = *(const bf16x8*)(B + (ib + r16) * (size_t)K + kk + g4 * 8);
    #pragma unroll
    for (int cg = 0; cg < 8; ++cg){
      bf16x8 a = *(const bf16x8*)(A + (size_t)(cg * 16 + r16) * K + kk + g4 * 8);
      acc[cg] = mfma16(a, b, acc[cg]);
    }
  }
  const int jp = w * 16 + r16;
  u16* tb = outT + (size_t)blockIdx.x * 8192;
  #pragma unroll
  for (int cg = 0; cg < 8; ++cg)
    #pragma unroll
    for (int q = 0; q < 4; ++q){
      const int c = cg * 16 + g4 * 4 + q;
      tb[c * 64 + (jp ^ ((c & 7) << 3))] = f2bf(acc[cg][q]);
    }
}

// ---------------- attention: LDS dbuf, 4 waves x 32 rows, 4 blocks/CU, pk prefetch ----------------
// PART tile layout (16-row tile, 2048 u16): elem(r,c) at ((c>>4)*4 + (r&3))*64 + (r>>2)*16 + (c&15)
template<int S>
__global__ __launch_bounds__(256, 4) void k_attn(
    const unsigned char* __restrict__ pk,
    const u16* __restrict__ whT_all,       // tiled-swizzled [H][128 tiles][8192] u16
    const float* __restrict__ f1_all, const float* __restrict__ f2_all,
    const unsigned int* __restrict__ fkey,
    u16* __restrict__ part, float* __restrict__ pl)
{
  __shared__ __align__(16) u16 tile[2][8192];   // 2 x 16 KB
  const int h = blockIdx.z;
  const int s = blockIdx.y;
  const float* f2 = f2_all + (size_t)h * N;
  const float fmax = fkey_dec(fkey[h]);
  const int w = threadIdx.x >> 6;
  const int lane = threadIdx.x & 63;
  const int r16 = lane & 15, g4 = lane >> 4;
  const size_t ibase = (size_t)blockIdx.x * 128 + w * 32;
  constexpr int TPS = 128 / S;
  const int t0 = s * TPS, t1 = t0 + TPS;
  const char* gt = (const char*)whT_all + (size_t)h * 2097152;

  float c1[2], c2[2], lsum[2];
  f32x4 acc[2][8];
  #pragma unroll
  for (int rg = 0; rg < 2; ++rg){
    const float f1v = f1_all[(size_t)h * N + ibase + rg * 16 + r16];
    const float y = f1v + fmax;
    const float mrow = fmaxf(y, 0.2f * y);
    c1[rg] = f1v - mrow;
    c2[rg] = fmaf(0.2f, f1v, -mrow);
    lsum[rg] = 0.f;
    #pragma unroll
    for (int ct = 0; ct < 8; ++ct) acc[rg][ct] = (f32x4){0,0,0,0};
  }

  const int swz = (r16 & 7) << 3;
  const int off0 = r16 * 64 + ((g4 * 8) ^ swz);
  const unsigned char* pkr0 = pk + (ibase + r16) * 1024 + g4 * 2;
  const unsigned char* pkr1 = pkr0 + 16 * 1024;

  auto stage = [&](int buf, int tt){
    const char* src = gt + (size_t)tt * 16384 + w * 4096 + lane * 16;
    char* dst = ((char*)&tile[0][0]) + buf * 16384 + w * 4096;
    #pragma unroll
    for (int k = 0; k < 4; ++k)
      gload16(src + k * 1024, dst + k * 1024);
  };

  stage(0, t0);
  unsigned int bits0 = *(const unsigned short*)(pkr0 + t0 * 8);
  unsigned int bits1 = *(const unsigned short*)(pkr1 + t0 * 8);

  for (int t = t0; t < t1; ++t){
    const int cur = (t - t0) & 1;
    __syncthreads();                        // tile[cur] ready, tile[cur^1] free
    if (t + 1 < t1) stage(cur ^ 1, t + 1);  // DMA next tile under compute
    unsigned int nb0 = bits0, nb1 = bits1;
    if (t + 1 < t1){                        // prefetch next-tile adjacency bits
      nb0 = *(const unsigned short*)(pkr0 + (t + 1) * 8);
      nb1 = *(const unsigned short*)(pkr1 + (t + 1) * 8);
    }
    const u16* lp = &tile[cur][0];
    #pragma unroll
    for (int k2 = 0; k2 < 2; ++k2){
      const int offk = off0 ^ (k2 << 5);
      bf16x8 bfr[8];                        // batch ds_reads before score VALU
      #pragma unroll
      for (int ct = 0; ct < 8; ++ct) bfr[ct] = *(const bf16x8*)(lp + offk + ct * 1024);
      const float* fjp = f2 + t * 64 + k2 * 32 + g4 * 8;
      f32x4 fa = *(const f32x4*)(fjp);
      f32x4 fb = *(const f32x4*)(fjp + 4);
      bf16x8 pa0, pa1;
      {
        const unsigned int bb = (bits0 >> (k2 * 8)) & 0xFFu;
        union { __hip_bfloat162 h2[4]; bf16x8 v8; } u;
        #pragma unroll
        for (int xp = 0; xp < 4; ++xp){
          const float s0 = (xp < 2) ? fa[2 * xp] : fb[2 * xp - 4];
          const float s1 = (xp < 2) ? fa[2 * xp + 1] : fb[2 * xp - 3];
          float p0 = __builtin_amdgcn_exp2f(fmaxf(s0 + c1[0], fmaf(s0, 0.2f, c2[0])));
          float p1 = __builtin_amdgcn_exp2f(fmaxf(s1 + c1[0], fmaf(s1, 0.2f, c2[0])));
          p0 = ((bb >> (2 * xp)) & 1u) ? p0 : 0.f;
          p1 = ((bb >> (2 * xp + 1)) & 1u) ? p1 : 0.f;
          lsum[0] += p0 + p1;
          u.h2[xp] = __float22bfloat162_rn(make_float2(p0, p1));
        }
        pa0 = u.v8;
      }
      {
        const unsigned int bb = (bits1 >> (k2 * 8)) & 0xFFu;
        union { __hip_bfloat162 h2[4]; bf16x8 v8; } u;
        #pragma unroll
        for (int xp = 0; xp < 4; ++xp){
          const float s0 = (xp < 2) ? fa[2 * xp] : fb[2 * xp - 4];
          const float s1 = (xp < 2) ? fa[2 * xp + 1] : fb[2 * xp - 3];
          float p0 = __builtin_amdgcn_exp2f(fmaxf(s0 + c1[1], fmaf(s0, 0.2f, c2[1])));
          float p1 = __builtin_amdgcn_exp2f(fmaxf(s1 + c1[1], fmaf(s1, 0.2f, c2[1])));
          p0 = ((bb >> (2 * xp)) & 1u) ? p0 : 0.f;
          p1 = ((bb >> (2 * xp + 1)) & 1u) ? p1 : 0.f;
          lsum[1] += p0 + p1;
          u.h2[xp] = __float22bfloat162_rn(make_float2(p0, p1));
        }
        pa1 = u.v8;
      }
      #pragma unroll
      for (int ct = 0; ct < 8; ++ct){
        acc[0][ct] = mfma16(pa0, bfr[ct], acc[0][ct]);
        acc[1][ct] = mfma16(pa1, bfr[ct], acc[1][ct]);
      }
    }
    bits0 = nb0; bits1 = nb1;
  }

  const int plane = h * S + s;
  #pragma unroll
  for (int rg = 0; rg < 2; ++rg){
    const int tile_row = (int)(ibase >> 4) + rg;
    u16* pp = part + ((size_t)plane * 512 + tile_row) * 2048;
    #pragma unroll
    for (int ct = 0; ct < 8; ++ct)
      #pragma unroll
      for (int q = 0; q < 4; ++q)
        pp[(ct * 4 + q) * 64 + lane] = f2bf(acc[rg][ct][q]);
    float lv = lsum[rg];
    lv += __shfl_xor(lv, 16); lv += __shfl_xor(lv, 32);
    if (lane < 16) pl[(size_t)plane * N + ibase + rg * 16 + lane] = lv;
  }
}

// ---------------- merge partials: sum, normalize, elu, write ----------------
template<int S, bool L2>
__global__ __launch_bounds__(256) void k_attn_merge(
    const u16* __restrict__ part, const float* __restrict__ pl,
    u16* __restrict__ hbf, float* __restrict__ nodeout, u16* __restrict__ comb)
{
  const int h = blockIdx.y;
  const int idx = blockIdx.x * 256 + threadIdx.x;
  const int i = idx >> 5, c4 = (idx & 31) * 4;
  const int tl = i >> 4, r = i & 15;
  const size_t off = (size_t)tl * 2048 + (size_t)(((c4 >> 4) * 4 + (r & 3)) * 64 + ((r >> 2) & 3) * 16 + (c4 & 15));
  f32x4 a = (f32x4){0,0,0,0};
  float L = 0.f;
  #pragma unroll
  for (int s = 0; s < S; ++s){
    const size_t plane = h * S + s;
    u16x4 v = *(const u16x4*)(part + plane * (size_t)(N * 128) + off);
    a[0] += bf2f(v[0]); a[1] += bf2f(v[1]); a[2] += bf2f(v[2]); a[3] += bf2f(v[3]);
    L += pl[plane * (size_t)N + i];
  }
  const float linv = 1.f / L;
  u16x4 hv;
  #pragma unroll
  for (int e = 0; e < 4; ++e){
    float o = a[e] * linv;
    o = (o > 0.f) ? o : (__expf(o) - 1.f);
    a[e] = o;
    hv[e] = f2bf(o);
  }
  if constexpr (!L2){
    *(u16x4*)(hbf + (size_t)i * 256 + h * 128 + c4) = hv;
  } else {
    *(f32x4*)(nodeout + (size_t)i * 128 + c4) = a;
    *(u16x4*)(comb + (size_t)i * 256 + 128 + c4) = hv;
  }
}

// ---------------- row-major GEMM + bias + relu (+optional column-sum) ----------------
template<bool STORE, bool COLSUM>
__global__ __launch_bounds__(256) void k_gemm_row(
    const u16* __restrict__ A, const u16* __restrict__ BT,
    const float* __restrict__ bias,
    u16* __restrict__ out, float* __restrict__ csum,
    int K, int Ntot)
{
  const int lane = threadIdx.x & 63, w = threadIdx.x >> 6;
  const int r16 = lane & 15, g4 = lane >> 4;
  const size_t rbase = (size_t)blockIdx.x * 64 + w * 16;
  const int cbase = blockIdx.y * 128;
  f32x4 acc[8];
  #pragma unroll
  for (int ct = 0; ct < 8; ++ct) acc[ct] = (f32x4){0,0,0,0};
  for (int kk = 0; kk < K; kk += 32){
    bf16x8 af = *(const bf16x8*)(A + (rbase + r16) * (size_t)K + kk + g4 * 8);
    #pragma unroll
    for (int ct = 0; ct < 8; ++ct){
      bf16x8 bfr = *(const bf16x8*)(BT + (size_t)(cbase + ct * 16 + r16) * K + kk + g4 * 8);
      acc[ct] = mfma16(af, bfr, acc[ct]);
    }
  }
  #pragma unroll
  for (int ct = 0; ct < 8; ++ct){
    const float bv = bias[cbase + ct * 16 + r16];
    float sacc = 0.f;
    #pragma unroll
    for (int q = 0; q < 4; ++q){
      float v = acc[ct][q] + bv;
      v = fmaxf(v, 0.f);
      if constexpr (STORE)
        out[(rbase + g4 * 4 + q) * (size_t)Ntot + cbase + ct * 16 + r16] = f2bf(v);
      sacc += v;
    }
    if constexpr (COLSUM){
      sacc += __shfl_xor(sacc, 16); sacc += __shfl_xor(sacc, 32);
      if (lane < 16) atomicAdd(&csum[cbase + ct * 16 + lane], sacc);
    }
  }
}

__global__ void k_final(const float* __restrict__ csum, float* __restrict__ out){
  out[threadIdx.x] = csum[threadIdx.x] * (1.f / 8192.f);
}

// ---------------- host launch ----------------
extern "C" void kernel_launch(void* const* d_in, const int* in_sizes, int n_in,
                              void* d_out, int out_size, void* d_ws, size_t ws_size,
                              hipStream_t stream) {
  const int*   adj = (const int*)d_in[0];
  const float* x   = (const float*)d_in[1];
  const float* Wh  = (const float*)d_in[2];
  const float* ah  = (const float*)d_in[3];
  const float* Wo  = (const float*)d_in[4];
  const float* ao  = (const float*)d_in[5];
  const float* g1  = (const float*)d_in[6];
  const float* b1  = (const float*)d_in[7];
  const float* g2  = (const float*)d_in[8];
  const float* b2  = (const float*)d_in[9];
  float* outp = (float*)d_out;
  char* ws = (char*)d_ws;

  constexpr size_t PK   = 0;          //  8,388,608  packed adj bits (permuted)
  constexpr size_t PART = 8388608;    // 33,554,432  bf16 partials [16 planes][512 tiles][2048]
  constexpr size_t PL   = 41943040;   //    524,288  l partials [16][8192] f32
  constexpr size_t XBF  = 42467328;   //  2,097,152  x bf16
  constexpr size_t WHT1 = 44564480;   //  4,194,304  Wh^T L1 tiled-swz [2][128][8192]u16
  constexpr size_t WHT2 = 48758784;   //  2,097,152  Wh^T L2 tiled-swz
  constexpr size_t HBF  = 50855936;   //  4,194,304  h bf16 [8192][256]
  constexpr size_t COMB = 55050240;   //  4,194,304  combined [8192][256]
  constexpr size_t H1RO = WHT1;       //  alias: WhT1 dead after attn1
  constexpr size_t F1S  = 59244544;   //     65,536
  constexpr size_t F2S  = 59310080;   //     65,536
  constexpr size_t CSUM = 59375616;   //        512
  constexpr size_t WTH  = 59376128;   //     65,536
  constexpr size_t WOT  = 59441664;   //     65,536
  constexpr size_t G1T  = 59507200;   //    131,072
  constexpr size_t G2T  = 59638272;   //     65,536
  constexpr size_t WA   = 59703808;   //      4,096
  constexpr size_t FKEY = 59707904;   //         16

  k_pack<<<512, 256, 0, stream>>>(adj, (unsigned char*)(ws + PK));
  k_prep<<<1668, 256, 0, stream>>>(x, Wh, Wo, g1, g2, ah, ao,
      (u16*)(ws + XBF), (u16*)(ws + COMB), (u16*)(ws + WTH), (u16*)(ws + WOT),
      (u16*)(ws + G1T), (u16*)(ws + G2T),
      (float*)(ws + WA), (unsigned int*)(ws + FKEY), (float*)(ws + CSUM));

  // layer 1
  k_gemv1<<<dim3(512, 2), 256, 0, stream>>>(x, (const float*)(ws + WA),
      (float*)(ws + F1S), (float*)(ws + F2S), (unsigned int*)(ws + FKEY));
  k_gemm_at<<<dim3(128, 2), 256, 0, stream>>>((const u16*)(ws + WTH), (const u16*)(ws + XBF),
                                              (u16*)(ws + WHT1), 128);
  k_attn<8><<<dim3(64, 8, 2), 256, 0, stream>>>(
      (const unsigned char*)(ws + PK), (const u16*)(ws + WHT1),
      (const float*)(ws + F1S), (const float*)(ws + F2S), (const unsigned int*)(ws + FKEY),
      (u16*)(ws + PART), (float*)(ws + PL));
  k_attn_merge<8, false><<<dim3(1024, 2), 256, 0, stream>>>(
      (const u16*)(ws + PART), (const float*)(ws + PL),
      (u16*)(ws + HBF), nullptr, nullptr);

  // layer 2
  k_gemv2<<<dim3(512, 1), 256, 0, stream>>>((const u16*)(ws + HBF),
      (const float*)(ws + WA) + 512, (const float*)(ws + WA) + 768,
      (float*)(ws + F1S), (float*)(ws + F2S), (unsigned int*)(ws + FKEY) + 2);
  k_gemm_at<<<dim3(128, 1), 256, 0, stream>>>((const u16*)(ws + WOT), (const u16*)(ws + HBF),
                                              (u16*)(ws + WHT2), 256);
  k_attn<16><<<dim3(64, 16, 1), 256, 0, stream>>>(
      (const unsigned char*)(ws + PK), (const u16*)(ws + WHT2),
      (const float*)(ws + F1S), (const float*)(ws + F2S), (const unsigned int*)(ws + FKEY) + 2,
      (u16*)(ws + PART), (float*)(ws + PL));
  k_attn_merge<16, true><<<dim3(1024, 1), 256, 0, stream>>>(
      (const u16*)(ws + PART), (const float*)(ws + PL),
      nullptr, outp, (u16*)(ws + COMB));

  // readout MLP
  k_gemm_row<true, false><<<dim3(128, 2), 256, 0, stream>>>(
      (const u16*)(ws + COMB), (const u16*)(ws + G1T), b1,
      (u16*)(ws + H1RO), nullptr, 256, 256);
  k_gemm_row<false, true><<<dim3(128, 1), 256, 0, stream>>>(
      (const u16*)(ws + H1RO), (const u16*)(ws + G2T), b2,
      nullptr, (float*)(ws + CSUM), 256, 128);
  k_final<<<1, 128, 0, stream>>>((const float*)(ws + CSUM), outp + (size_t)N * 128);
}